// Round 1
// baseline (185.901 us; speedup 1.0000x reference)
//
#include <hip/hip_runtime.h>
#include <math.h>

#define NP 4
#define NN 8192
#define NM 8192

// ws layout (floats):
//   A (cad transformed, packed x,y,z,h=0.5|v|^2):  float4[NP*NM]   at 0
//   B (cam packed):                                float4[NP*NN]   at NP*NM (float4 idx)
//   minA: float[NP*NM]   at float offset (NP*NM + NP*NN)*4
//   minB: float[NP*NN]   after minA
#define MINA_OFF ((NP * NM + NP * NN) * 4)
#define MINB_OFF (MINA_OFF + NP * NM)

#define TQ 4        // queries per thread
#define QT 1024     // queries per block (256 * TQ)
#define SPLITS 16   // target-dim splits
#define CHUNK 512   // targets staged in LDS (== NN/SPLITS)

__device__ inline void make_transform(const float* __restrict__ quat,
                                      const float* __restrict__ tra,
                                      int p, float T[12]) {
    float q0 = quat[p * 4 + 0], q1 = quat[p * 4 + 1];
    float q2 = quat[p * 4 + 2], q3 = quat[p * 4 + 3];
    float inv = 1.0f / sqrtf(q0 * q0 + q1 * q1 + q2 * q2 + q3 * q3);
    float a = q0 * inv, b = q1 * inv, c = q2 * inv, d = q3 * inv;
    T[0] = 1.0f - 2.0f * c * c - 2.0f * d * d;
    T[1] = 2.0f * b * c - 2.0f * a * d;
    T[2] = 2.0f * a * c + 2.0f * b * d;
    T[3] = tra[p * 3 + 0];
    T[4] = 2.0f * b * c + 2.0f * a * d;
    T[5] = 1.0f - 2.0f * b * b - 2.0f * d * d;
    T[6] = 2.0f * c * d - 2.0f * a * b;
    T[7] = tra[p * 3 + 1];
    T[8] = 2.0f * b * d - 2.0f * a * c;
    T[9] = 2.0f * a * b + 2.0f * c * d;
    T[10] = 1.0f - 2.0f * b * b - 2.0f * c * c;
    T[11] = tra[p * 3 + 2];
}

__global__ __launch_bounds__(256) void prep_kernel(
    const float* __restrict__ cam, const float* __restrict__ cad,
    const float* __restrict__ quat, const float* __restrict__ tra,
    float* __restrict__ ws, float* __restrict__ out) {
    int idx = blockIdx.x * 256 + threadIdx.x;  // [0, NP*(NM+NN))
    const float INF = __uint_as_float(0x7f800000u);

    if (idx < NP * NM) {
        int p = idx >> 13;  // idx / NM
        int m = idx & (NM - 1);
        float T[12];
        make_transform(quat, tra, p, T);
        float x = cad[(p * NM + m) * 3 + 0];
        float y = cad[(p * NM + m) * 3 + 1];
        float z = cad[(p * NM + m) * 3 + 2];
        float vx = fmaf(T[0], x, fmaf(T[1], y, fmaf(T[2], z, T[3])));
        float vy = fmaf(T[4], x, fmaf(T[5], y, fmaf(T[6], z, T[7])));
        float vz = fmaf(T[8], x, fmaf(T[9], y, fmaf(T[10], z, T[11])));
        float h = 0.5f * (vx * vx + vy * vy + vz * vz);
        ((float4*)ws)[idx] = make_float4(vx, vy, vz, h);
        ws[MINA_OFF + idx] = INF;
    } else {
        int k = idx - NP * NM;
        int p = k >> 13;
        int n = k & (NN - 1);
        float vx = cam[(p * NN + n) * 3 + 0];
        float vy = cam[(p * NN + n) * 3 + 1];
        float vz = cam[(p * NN + n) * 3 + 2];
        float h = 0.5f * (vx * vx + vy * vy + vz * vz);
        ((float4*)ws)[idx] = make_float4(vx, vy, vz, h);
        ws[MINB_OFF + k] = INF;
    }

    // threads 0..63 (part-0 cad threads) also emit the transforms output
    if (idx < 64) {
        int p2 = idx >> 4;
        int r = (idx >> 2) & 3;
        int c = idx & 3;
        float T[12];
        make_transform(quat, tra, p2, T);
        float v;
        if (r == 3)
            v = (c == 3) ? 1.0f : 0.0f;
        else
            v = T[r * 4 + c];
        out[1 + idx] = v;
    }
}

__global__ __launch_bounds__(256) void minpass_kernel(float* __restrict__ ws) {
    int tid = threadIdx.x;
    int p = blockIdx.z >> 1;
    int role = blockIdx.z & 1;

    const float4* Q;
    const float4* T;
    float* minarr;
    if (role == 0) {  // queries = cad(A), targets = cam(B) -> minA
        Q = (const float4*)ws + p * NM;
        T = (const float4*)ws + NP * NM + p * NN;
        minarr = ws + MINA_OFF + p * NM;
    } else {  // queries = cam(B), targets = cad(A) -> minB
        Q = (const float4*)ws + NP * NM + p * NN;
        T = (const float4*)ws + p * NM;
        minarr = ws + MINB_OFF + p * NN;
    }

    __shared__ float4 sT[CHUNK];

    int q0 = blockIdx.x * QT + tid;
    float4 q[TQ];
    float tmin[TQ];
#pragma unroll
    for (int k = 0; k < TQ; ++k) {
        q[k] = Q[q0 + k * 256];
        tmin[k] = __uint_as_float(0x7f800000u);
    }

    int tstart = blockIdx.y * CHUNK;
#pragma unroll
    for (int j = tid; j < CHUNK; j += 256) sT[j] = T[tstart + j];
    __syncthreads();

#pragma unroll 4
    for (int j = 0; j < CHUNK; ++j) {
        float4 t = sT[j];
#pragma unroll
        for (int k = 0; k < TQ; ++k) {
            float s = fmaf(-q[k].x, t.x, fmaf(-q[k].y, t.y, fmaf(-q[k].z, t.z, t.w)));
            tmin[k] = fminf(tmin[k], s);
        }
    }

#pragma unroll
    for (int k = 0; k < TQ; ++k) {
        float d2 = 2.0f * (q[k].w + tmin[k]);
        d2 = fmaxf(d2, 0.0f);
        atomicMin((unsigned int*)&minarr[q0 + k * 256], __float_as_uint(d2));
    }
}

__global__ __launch_bounds__(256) void finalize_kernel(
    const float* __restrict__ ws, const float* __restrict__ w,
    float* __restrict__ out) {
    int tid = threadIdx.x;
    float acc = 0.0f;
    const float* minA = ws + MINA_OFF;
    const float* minB = ws + MINB_OFF;
    for (int i = tid; i < NP * NM; i += 256) {
        acc += w[i >> 13] * sqrtf(minA[i]);
    }
    for (int i = tid; i < NP * NN; i += 256) {
        acc += w[i >> 13] * sqrtf(minB[i]);
    }
#pragma unroll
    for (int off = 32; off > 0; off >>= 1) acc += __shfl_down(acc, off, 64);
    __shared__ float wsum[4];
    if ((tid & 63) == 0) wsum[tid >> 6] = acc;
    __syncthreads();
    if (tid == 0)
        out[0] = (wsum[0] + wsum[1] + wsum[2] + wsum[3]) * (1.0f / 8192.0f);
}

extern "C" void kernel_launch(void* const* d_in, const int* in_sizes, int n_in,
                              void* d_out, int out_size, void* d_ws, size_t ws_size,
                              hipStream_t stream) {
    const float* cam = (const float*)d_in[0];   // (P, N, 3)
    const float* cad = (const float*)d_in[1];   // (P, M, 3)
    const float* w = (const float*)d_in[2];     // (P,)
    const float* quat = (const float*)d_in[3];  // (P, 4)
    const float* tra = (const float*)d_in[4];   // (P, 3, 1)
    float* out = (float*)d_out;
    float* ws = (float*)d_ws;

    prep_kernel<<<(NP * (NM + NN)) / 256, 256, 0, stream>>>(cam, cad, quat, tra, ws, out);

    dim3 grid(NM / QT, SPLITS, 2 * NP);
    minpass_kernel<<<grid, 256, 0, stream>>>(ws);

    finalize_kernel<<<1, 256, 0, stream>>>(ws, w, out);
}

// Round 2
// 109.349 us; speedup vs baseline: 1.7001x; 1.7001x over previous
//
#include <hip/hip_runtime.h>
#include <math.h>

#define NP 4
#define NN 8192
#define NM 8192

// ws layout (floats):
//   A (cad transformed, packed x,y,z,h=0.5|v|^2):  float4[NP*NM]   at 0
//   B (cam packed):                                float4[NP*NN]   at NP*NM (float4 idx)
//   minA: float[NP*NM]   at float offset (NP*NM + NP*NN)*4
//   minB: float[NP*NN]   after minA (contiguous with minA)
#define MINA_OFF ((NP * NM + NP * NN) * 4)
#define MINB_OFF (MINA_OFF + NP * NM)

#define TQ 4        // queries per thread
#define QT 1024     // queries per block (256 * TQ)
#define SPLITS 16   // target-dim splits
#define CHUNK 512   // targets staged in LDS (== NN/SPLITS)

#define RED_BLOCKS 128  // finalize reduction blocks

__device__ inline void make_transform(const float* __restrict__ quat,
                                      const float* __restrict__ tra,
                                      int p, float T[12]) {
    float q0 = quat[p * 4 + 0], q1 = quat[p * 4 + 1];
    float q2 = quat[p * 4 + 2], q3 = quat[p * 4 + 3];
    float inv = 1.0f / sqrtf(q0 * q0 + q1 * q1 + q2 * q2 + q3 * q3);
    float a = q0 * inv, b = q1 * inv, c = q2 * inv, d = q3 * inv;
    T[0] = 1.0f - 2.0f * c * c - 2.0f * d * d;
    T[1] = 2.0f * b * c - 2.0f * a * d;
    T[2] = 2.0f * a * c + 2.0f * b * d;
    T[3] = tra[p * 3 + 0];
    T[4] = 2.0f * b * c + 2.0f * a * d;
    T[5] = 1.0f - 2.0f * b * b - 2.0f * d * d;
    T[6] = 2.0f * c * d - 2.0f * a * b;
    T[7] = tra[p * 3 + 1];
    T[8] = 2.0f * b * d - 2.0f * a * c;
    T[9] = 2.0f * a * b + 2.0f * c * d;
    T[10] = 1.0f - 2.0f * b * b - 2.0f * c * c;
    T[11] = tra[p * 3 + 2];
}

__global__ __launch_bounds__(256) void prep_kernel(
    const float* __restrict__ cam, const float* __restrict__ cad,
    const float* __restrict__ quat, const float* __restrict__ tra,
    float* __restrict__ ws, float* __restrict__ out) {
    int idx = blockIdx.x * 256 + threadIdx.x;  // [0, NP*(NM+NN))
    const float INF = __uint_as_float(0x7f800000u);

    if (idx < NP * NM) {
        int p = idx >> 13;  // idx / NM
        int m = idx & (NM - 1);
        float T[12];
        make_transform(quat, tra, p, T);
        float x = cad[(p * NM + m) * 3 + 0];
        float y = cad[(p * NM + m) * 3 + 1];
        float z = cad[(p * NM + m) * 3 + 2];
        float vx = fmaf(T[0], x, fmaf(T[1], y, fmaf(T[2], z, T[3])));
        float vy = fmaf(T[4], x, fmaf(T[5], y, fmaf(T[6], z, T[7])));
        float vz = fmaf(T[8], x, fmaf(T[9], y, fmaf(T[10], z, T[11])));
        float h = 0.5f * (vx * vx + vy * vy + vz * vz);
        ((float4*)ws)[idx] = make_float4(vx, vy, vz, h);
        ws[MINA_OFF + idx] = INF;
    } else {
        int k = idx - NP * NM;
        int p = k >> 13;
        int n = k & (NN - 1);
        float vx = cam[(p * NN + n) * 3 + 0];
        float vy = cam[(p * NN + n) * 3 + 1];
        float vz = cam[(p * NN + n) * 3 + 2];
        float h = 0.5f * (vx * vx + vy * vy + vz * vz);
        ((float4*)ws)[idx] = make_float4(vx, vy, vz, h);
        ws[MINB_OFF + k] = INF;
    }

    // threads 0..63 (part-0 cad threads) also emit the transforms output;
    // thread 64 zeroes the objective accumulator (harness poisons d_out).
    if (idx < 64) {
        int p2 = idx >> 4;
        int r = (idx >> 2) & 3;
        int c = idx & 3;
        float T[12];
        make_transform(quat, tra, p2, T);
        float v;
        if (r == 3)
            v = (c == 3) ? 1.0f : 0.0f;
        else
            v = T[r * 4 + c];
        out[1 + idx] = v;
    } else if (idx == 64) {
        out[0] = 0.0f;
    }
}

__global__ __launch_bounds__(256) void minpass_kernel(float* __restrict__ ws) {
    int tid = threadIdx.x;
    int p = blockIdx.z >> 1;
    int role = blockIdx.z & 1;

    const float4* Q;
    const float4* T;
    float* minarr;
    if (role == 0) {  // queries = cad(A), targets = cam(B) -> minA
        Q = (const float4*)ws + p * NM;
        T = (const float4*)ws + NP * NM + p * NN;
        minarr = ws + MINA_OFF + p * NM;
    } else {  // queries = cam(B), targets = cad(A) -> minB
        Q = (const float4*)ws + NP * NM + p * NN;
        T = (const float4*)ws + p * NM;
        minarr = ws + MINB_OFF + p * NN;
    }

    __shared__ float4 sT[CHUNK];

    int q0 = blockIdx.x * QT + tid;
    float4 q[TQ];
    float tmin[TQ];
#pragma unroll
    for (int k = 0; k < TQ; ++k) {
        q[k] = Q[q0 + k * 256];
        tmin[k] = __uint_as_float(0x7f800000u);
    }

    int tstart = blockIdx.y * CHUNK;
#pragma unroll
    for (int j = tid; j < CHUNK; j += 256) sT[j] = T[tstart + j];
    __syncthreads();

#pragma unroll 4
    for (int j = 0; j < CHUNK; ++j) {
        float4 t = sT[j];
#pragma unroll
        for (int k = 0; k < TQ; ++k) {
            float s = fmaf(-q[k].x, t.x, fmaf(-q[k].y, t.y, fmaf(-q[k].z, t.z, t.w)));
            tmin[k] = fminf(tmin[k], s);
        }
    }

#pragma unroll
    for (int k = 0; k < TQ; ++k) {
        float d2 = 2.0f * (q[k].w + tmin[k]);
        d2 = fmaxf(d2, 0.0f);
        atomicMin((unsigned int*)&minarr[q0 + k * 256], __float_as_uint(d2));
    }
}

__global__ __launch_bounds__(256) void finalize_kernel(
    const float* __restrict__ ws, const float* __restrict__ w,
    float* __restrict__ out) {
    // minA (NP*NM) and minB (NP*NN) are contiguous: 65536 floats at MINA_OFF.
    // part index for element j: (j >> 13) & 3  (minB follows minA, same layout)
    const float* vals = ws + MINA_OFF;
    int i = blockIdx.x * 256 + threadIdx.x;  // [0, 32768)
    int tid = threadIdx.x;

    float w0 = w[0], w1 = w[1], w2 = w[2], w3 = w[3];
    float wl[4] = {w0, w1, w2, w3};

    int i2 = i + 32768;
    float acc = wl[(i >> 13) & 3] * sqrtf(vals[i]) +
                wl[(i2 >> 13) & 3] * sqrtf(vals[i2]);

#pragma unroll
    for (int off = 32; off > 0; off >>= 1) acc += __shfl_down(acc, off, 64);

    __shared__ float wsum[4];
    if ((tid & 63) == 0) wsum[tid >> 6] = acc;
    __syncthreads();
    if (tid == 0) {
        float blocksum = (wsum[0] + wsum[1] + wsum[2] + wsum[3]) * (1.0f / 8192.0f);
        atomicAdd(out, blocksum);
    }
}

extern "C" void kernel_launch(void* const* d_in, const int* in_sizes, int n_in,
                              void* d_out, int out_size, void* d_ws, size_t ws_size,
                              hipStream_t stream) {
    const float* cam = (const float*)d_in[0];   // (P, N, 3)
    const float* cad = (const float*)d_in[1];   // (P, M, 3)
    const float* w = (const float*)d_in[2];     // (P,)
    const float* quat = (const float*)d_in[3];  // (P, 4)
    const float* tra = (const float*)d_in[4];   // (P, 3, 1)
    float* out = (float*)d_out;
    float* ws = (float*)d_ws;

    prep_kernel<<<(NP * (NM + NN)) / 256, 256, 0, stream>>>(cam, cad, quat, tra, ws, out);

    dim3 grid(NM / QT, SPLITS, 2 * NP);
    minpass_kernel<<<grid, 256, 0, stream>>>(ws);

    finalize_kernel<<<RED_BLOCKS, 256, 0, stream>>>(ws, w, out);
}

// Round 3
// 107.207 us; speedup vs baseline: 1.7340x; 1.0200x over previous
//
#include <hip/hip_runtime.h>
#include <math.h>

#define NP 4
#define NN 8192
#define NM 8192

// ws layout (floats): minA float[NP*NM] at 0, minB float[NP*NN] right after.
#define MINB_OFF (NP * NM)

#define TQ 8        // queries per thread
#define QT 2048     // queries per block (256 * TQ)
#define SPLITS 16   // target-dim splits
#define CHUNK 512   // targets staged in LDS (== NN/SPLITS)

#define RED_BLOCKS 128  // finalize reduction blocks

__device__ inline float min3f(float a, float b, float c) {
    float d;
    asm("v_min3_f32 %0, %1, %2, %3" : "=v"(d) : "v"(a), "v"(b), "v"(c));
    return d;
}

__device__ inline void make_transform(const float* __restrict__ quat,
                                      const float* __restrict__ tra,
                                      int p, float T[12]) {
    float q0 = quat[p * 4 + 0], q1 = quat[p * 4 + 1];
    float q2 = quat[p * 4 + 2], q3 = quat[p * 4 + 3];
    float inv = 1.0f / sqrtf(q0 * q0 + q1 * q1 + q2 * q2 + q3 * q3);
    float a = q0 * inv, b = q1 * inv, c = q2 * inv, d = q3 * inv;
    T[0] = 1.0f - 2.0f * c * c - 2.0f * d * d;
    T[1] = 2.0f * b * c - 2.0f * a * d;
    T[2] = 2.0f * a * c + 2.0f * b * d;
    T[3] = tra[p * 3 + 0];
    T[4] = 2.0f * b * c + 2.0f * a * d;
    T[5] = 1.0f - 2.0f * b * b - 2.0f * d * d;
    T[6] = 2.0f * c * d - 2.0f * a * b;
    T[7] = tra[p * 3 + 1];
    T[8] = 2.0f * b * d - 2.0f * a * c;
    T[9] = 2.0f * a * b + 2.0f * c * d;
    T[10] = 1.0f - 2.0f * b * b - 2.0f * c * c;
    T[11] = tra[p * 3 + 2];
}

// 64 blocks x 256 threads: init min arrays to +inf (float4 stores), block 0
// also writes the 4x4x4 transforms to out[1..64] and zeroes out[0].
__global__ __launch_bounds__(256) void init_kernel(
    const float* __restrict__ quat, const float* __restrict__ tra,
    float* __restrict__ ws, float* __restrict__ out) {
    int idx = blockIdx.x * 256 + threadIdx.x;  // [0, 16384)
    const float INF = __uint_as_float(0x7f800000u);
    ((float4*)ws)[idx] = make_float4(INF, INF, INF, INF);

    if (blockIdx.x == 0) {
        int t = threadIdx.x;
        if (t < 64) {
            int p2 = t >> 4;
            int r = (t >> 2) & 3;
            int c = t & 3;
            float T[12];
            make_transform(quat, tra, p2, T);
            float v;
            if (r == 3)
                v = (c == 3) ? 1.0f : 0.0f;
            else
                v = T[r * 4 + c];
            out[1 + t] = v;
        } else if (t == 64) {
            out[0] = 0.0f;
        }
    }
}

// grid (NM/QT, SPLITS, 2*NP). Fused: transforms raw points on the fly
// (queries for role 0 = cad, targets for role 1 = cad), no packed arrays.
__global__ __launch_bounds__(256) void chamfer_kernel(
    const float* __restrict__ cam, const float* __restrict__ cad,
    const float* __restrict__ quat, const float* __restrict__ tra,
    float* __restrict__ ws) {
    int tid = threadIdx.x;
    int p = blockIdx.z >> 1;
    int role = blockIdx.z & 1;

    float T[12];
    make_transform(quat, tra, p, T);

    const float* Qsrc;
    const float* Tsrc;
    float* minarr;
    if (role == 0) {  // queries = transformed cad, targets = cam -> minA
        Qsrc = cad + p * NM * 3;
        Tsrc = cam + p * NN * 3;
        minarr = ws + p * NM;
    } else {  // queries = cam, targets = transformed cad -> minB
        Qsrc = cam + p * NN * 3;
        Tsrc = cad + p * NM * 3;
        minarr = ws + MINB_OFF + p * NN;
    }

    __shared__ float4 sT[CHUNK];

    const float INF = __uint_as_float(0x7f800000u);
    int q0 = blockIdx.x * QT + tid;
    float4 q[TQ];
    float tmin[TQ];
#pragma unroll
    for (int k = 0; k < TQ; ++k) {
        int m = q0 + k * 256;
        float x = Qsrc[m * 3 + 0];
        float y = Qsrc[m * 3 + 1];
        float z = Qsrc[m * 3 + 2];
        float vx, vy, vz;
        if (role == 0) {
            vx = fmaf(T[0], x, fmaf(T[1], y, fmaf(T[2], z, T[3])));
            vy = fmaf(T[4], x, fmaf(T[5], y, fmaf(T[6], z, T[7])));
            vz = fmaf(T[8], x, fmaf(T[9], y, fmaf(T[10], z, T[11])));
        } else {
            vx = x; vy = y; vz = z;
        }
        q[k] = make_float4(vx, vy, vz, 0.5f * (vx * vx + vy * vy + vz * vz));
        tmin[k] = INF;
    }

    int tstart = blockIdx.y * CHUNK;
#pragma unroll
    for (int j = tid; j < CHUNK; j += 256) {
        int t = tstart + j;
        float x = Tsrc[t * 3 + 0];
        float y = Tsrc[t * 3 + 1];
        float z = Tsrc[t * 3 + 2];
        float vx, vy, vz;
        if (role == 1) {
            vx = fmaf(T[0], x, fmaf(T[1], y, fmaf(T[2], z, T[3])));
            vy = fmaf(T[4], x, fmaf(T[5], y, fmaf(T[6], z, T[7])));
            vz = fmaf(T[8], x, fmaf(T[9], y, fmaf(T[10], z, T[11])));
        } else {
            vx = x; vy = y; vz = z;
        }
        sT[j] = make_float4(vx, vy, vz, 0.5f * (vx * vx + vy * vy + vz * vz));
    }
    __syncthreads();

#pragma unroll 4
    for (int j = 0; j < CHUNK; j += 2) {
        float4 t0 = sT[j];
        float4 t1 = sT[j + 1];
#pragma unroll
        for (int k = 0; k < TQ; ++k) {
            float s0 = fmaf(-q[k].x, t0.x, fmaf(-q[k].y, t0.y, fmaf(-q[k].z, t0.z, t0.w)));
            float s1 = fmaf(-q[k].x, t1.x, fmaf(-q[k].y, t1.y, fmaf(-q[k].z, t1.z, t1.w)));
            tmin[k] = min3f(tmin[k], s0, s1);
        }
    }

#pragma unroll
    for (int k = 0; k < TQ; ++k) {
        float d2 = 2.0f * (q[k].w + tmin[k]);
        d2 = fmaxf(d2, 0.0f);
        atomicMin((unsigned int*)&minarr[q0 + k * 256], __float_as_uint(d2));
    }
}

__global__ __launch_bounds__(256) void finalize_kernel(
    const float* __restrict__ ws, const float* __restrict__ w,
    float* __restrict__ out) {
    // minA (NP*NM) then minB (NP*NN), contiguous 65536 floats at ws[0].
    // part index for element j: (j >> 13) & 3 (same layout in both halves).
    const float* vals = ws;
    int i = blockIdx.x * 256 + threadIdx.x;  // [0, 32768)
    int tid = threadIdx.x;

    float wl[4] = {w[0], w[1], w[2], w[3]};

    int i2 = i + 32768;
    float acc = wl[(i >> 13) & 3] * sqrtf(vals[i]) +
                wl[(i2 >> 13) & 3] * sqrtf(vals[i2]);

#pragma unroll
    for (int off = 32; off > 0; off >>= 1) acc += __shfl_down(acc, off, 64);

    __shared__ float wsum[4];
    if ((tid & 63) == 0) wsum[tid >> 6] = acc;
    __syncthreads();
    if (tid == 0) {
        float blocksum = (wsum[0] + wsum[1] + wsum[2] + wsum[3]) * (1.0f / 8192.0f);
        atomicAdd(out, blocksum);
    }
}

extern "C" void kernel_launch(void* const* d_in, const int* in_sizes, int n_in,
                              void* d_out, int out_size, void* d_ws, size_t ws_size,
                              hipStream_t stream) {
    const float* cam = (const float*)d_in[0];   // (P, N, 3)
    const float* cad = (const float*)d_in[1];   // (P, M, 3)
    const float* w = (const float*)d_in[2];     // (P,)
    const float* quat = (const float*)d_in[3];  // (P, 4)
    const float* tra = (const float*)d_in[4];   // (P, 3, 1)
    float* out = (float*)d_out;
    float* ws = (float*)d_ws;

    init_kernel<<<64, 256, 0, stream>>>(quat, tra, ws, out);

    dim3 grid(NM / QT, SPLITS, 2 * NP);
    chamfer_kernel<<<grid, 256, 0, stream>>>(cam, cad, quat, tra, ws);

    finalize_kernel<<<RED_BLOCKS, 256, 0, stream>>>(ws, w, out);
}